// Round 4
// baseline (201.233 us; speedup 1.0000x reference)
//
#include <hip/hip_runtime.h>
#include <hip/hip_bf16.h>
#include <math.h>

#define HID 128
#define NRAD 6
#define TABN 4096          // nearest-neighbor table rows 0..TABN (row TABN = 0, x>=1 gate)
#define CUTOFF_INV 0.2f
#define MZ 95
#define MZP (MZ + 1)       // +1 sentinel row (index 95, huge-negative -> silu contribution == 0)
#define SENT ((MZ << 13) | (MZ << 20))
#define PAD 32             // padded-CSR slots per node (one 128B line); overflow -> spill list
#define OVF_CAP 65536
#define FTR 8              // ftab rows computed per block (W3 reuse x8)
#define LOG2E 1.4426950408889634f
#define LN2   0.6931471805599453f

typedef unsigned int uint32;

// ---------- K1: bf16 T1(+b_lin)/T2 (+sentinel row) + ftab + pos/z packing ----------
// T1/T2/ftab stored PRE-SCALED by log2(e); gather evaluates silu in exp2 domain.
__global__ void tabs_pack_k(const float* __restrict__ emb, const float* __restrict__ W_lin,
                            const float* __restrict__ freq, const float* __restrict__ W_rbf,
                            const float* __restrict__ b_rbf, const float* __restrict__ b_lin,
                            const float* __restrict__ pos, const int* __restrict__ z,
                            __hip_bfloat16* __restrict__ Tb, float* __restrict__ ftab,
                            float4* __restrict__ pos4,
                            int MAXZ, int N) {
    __shared__ float sh[FTR * HID];
    int h   = threadIdx.x;
    int bid = blockIdx.x;
    int nT  = 2 * (MAXZ + 1);
    int nF  = (TABN + FTR) / FTR;          // 513 blocks cover rows 0..4103 (clamped to TABN)
    if (bid < nT) {
        int zz = bid >> 1, s = bid & 1;
        if (zz == MAXZ) {                  // sentinel row: huge-neg => sigmoid==0 => zero contribution
            Tb[(size_t)(s * (MAXZ + 1) + zz) * HID + h] = __float2bfloat16(-86.5f);
            return;
        }
        sh[h] = emb[zz * HID + h];
        __syncthreads();
        const float* W = W_lin + (size_t)s * HID * HID;
        float acc = (s == 0) ? b_lin[h] : 0.f;   // fold bias into T1
#pragma unroll 8
        for (int k = 0; k < HID; ++k) acc = fmaf(sh[k], W[k * HID + h], acc);
        Tb[(size_t)(s * (MAXZ + 1) + zz) * HID + h] = __float2bfloat16(acc * LOG2E);
    } else if (bid < nT + nF) {
        int t0 = (bid - nT) * FTR;
        for (int r = 0; r < FTR; ++r) {
            int t = t0 + r;
            float rbf[NRAD];
            if (t == 0) {
#pragma unroll
                for (int k = 0; k < NRAD; ++k) rbf[k] = freq[k];   // lim x->0 env*sin(fx)=f
            } else if (t >= TABN) {
#pragma unroll
                for (int k = 0; k < NRAD; ++k) rbf[k] = 0.f;       // envelope gate x>=1
            } else {
                float x  = (float)t / (float)TABN;
                float x2 = x * x, x5 = x2 * x2 * x;
                float env = 1.f / x + x5 * (-28.f + x * (48.f + x * (-21.f)));
#pragma unroll
                for (int k = 0; k < NRAD; ++k) rbf[k] = env * sinf(freq[k] * x);
            }
            float pre = b_rbf[h];
#pragma unroll
            for (int k = 0; k < NRAD; ++k) pre = fmaf(rbf[k], W_rbf[k * HID + h], pre);
            sh[r * HID + h] = pre / (1.f + __expf(-pre));   // precise silu (once per table row)
        }
        __syncthreads();
        const float* W3 = W_lin + (size_t)2 * HID * HID;
        float acc[FTR];
#pragma unroll
        for (int r = 0; r < FTR; ++r) acc[r] = 0.f;
#pragma unroll 4
        for (int k = 0; k < HID; ++k) {
            float w = W3[k * HID + h];          // one load feeds 8 FMAs
#pragma unroll
            for (int r = 0; r < FTR; ++r) acc[r] = fmaf(sh[r * HID + k], w, acc[r]);
        }
        for (int r = 0; r < FTR; ++r) {
            int t = t0 + r;
            if (t <= TABN) ftab[(size_t)t * HID + h] = acc[r] * LOG2E;
        }
    } else {
        // pack phase: pos4[n] = {x, y, z, bits(z[n])} -- coalesced read, 16B write
        int n = (bid - nT - nF) * HID + h;
        if (n < N) {
            float4 p;
            p.x = pos[3 * n];
            p.y = pos[3 * n + 1];
            p.z = pos[3 * n + 2];
            p.w = __int_as_float(z[n]);
            pos4[n] = p;
        }
    }
}

// ---------- K2: edge pass -- 2 scattered 16B gathers + atomic rank + padded scatter ----------
__global__ void edge_k(const int* __restrict__ ei, const float4* __restrict__ pos4,
                       int* __restrict__ cnt, int* __restrict__ payload,
                       int* __restrict__ ovfcnt, int2* __restrict__ ovfbuf, int E) {
    int e = blockIdx.x * 256 + threadIdx.x;
    if (e >= E) return;
    int i = ei[e];
    int j = ei[E + e];
    float4 pi = pos4[i];                      // one 16B line: xyz + z-number
    float4 pj = pos4[j];
    float dx = pi.x - pj.x, dy = pi.y - pj.y, dz = pi.z - pj.z;
    float d  = sqrtf(dx * dx + dy * dy + dz * dz);
    float u  = fminf(d * CUTOFF_INV, 1.0f) * (float)TABN;
    int   ti = (int)(u + 0.5f);               // nearest
    if (ti > TABN) ti = TABN;
    int pl = ti | (__float_as_int(pi.w) << 13) | (__float_as_int(pj.w) << 20);
    int r  = atomicAdd(&cnt[j], 1);
    if (r < PAD) {
        payload[(size_t)j * PAD + r] = pl;
    } else {
        int o = atomicAdd(ovfcnt, 1);
        if (o < OVF_CAP) ovfbuf[o] = make_int2(j, pl);
    }
}

// 2^(-x) in one instruction (neg folded as src modifier)
__device__ __forceinline__ float exp2neg(float x) {
    float r; asm("v_exp_f32 %0, -%1" : "=v"(r) : "v"(x)); return r;
}

// payload select for iteration idx: lanes 0-31 -> edge 2*idx, lanes 32-63 -> edge 2*idx+1
#define PLSEL(pv_, idx_) (hi ? __builtin_amdgcn_readlane((pv_), 2 * (idx_) + 1) \
                             : __builtin_amdgcn_readlane((pv_), 2 * (idx_)))

// global ftab row fragment (16B per lane)
#define FLOAD(pl_) (*(const float4*)((const char*)ftab + (uint32)((((pl_) & 0x1FFF) << 9) + fb4)))

// LDS bf16-pair fragments for T1[zi], T2[zj]
#define TL(pl_, ua_, ub_) do {                                                 \
    int zi_ = ((pl_) >> 13) & 0x7F;                                            \
    int zj_ = ((pl_) >> 20) & 0x7F;                                            \
    ua_ = *(const uint2*)&sT[zi_ * (HID / 2) + l2];                            \
    ub_ = *(const uint2*)&sT[(MZP + zj_) * (HID / 2) + l2];                    \
} while (0)

// silu accumulate for 4 h-values (exp2 domain; sentinel rows underflow to exact 0 contribution)
#define COMPUTE(f_, ua_, ub_) do {                                                                 \
    float p0_ = __uint_as_float(ua_.x << 16)         + __uint_as_float(ub_.x << 16)         + f_.x; \
    float p1_ = __uint_as_float(ua_.x & 0xFFFF0000u) + __uint_as_float(ub_.x & 0xFFFF0000u) + f_.y; \
    float p2_ = __uint_as_float(ua_.y << 16)         + __uint_as_float(ub_.y << 16)         + f_.z; \
    float p3_ = __uint_as_float(ua_.y & 0xFFFF0000u) + __uint_as_float(ub_.y & 0xFFFF0000u) + f_.w; \
    ax = fmaf(p0_, __builtin_amdgcn_rcpf(1.f + exp2neg(p0_)), ax);                                 \
    ay = fmaf(p1_, __builtin_amdgcn_rcpf(1.f + exp2neg(p1_)), ay);                                 \
    az = fmaf(p2_, __builtin_amdgcn_rcpf(1.f + exp2neg(p2_)), az);                                 \
    aw = fmaf(p3_, __builtin_amdgcn_rcpf(1.f + exp2neg(p3_)), aw);                                 \
} while (0)

// ---------- K3 gather: 1 node/wave, 2 edges/iter, software-pipelined ----------
__launch_bounds__(1024)
__global__ void gather_k(const int* __restrict__ cnt, const int* __restrict__ payload,
                         const uint32* __restrict__ Tb32, const float* __restrict__ ftab,
                         const int* __restrict__ ovfcnt, const int2* __restrict__ ovfbuf,
                         float* __restrict__ out, int N) {
    __shared__ uint32 sT[2 * MZP * (HID / 2)];   // 49152 B, bf16 pairs (incl sentinel rows)
    int tid = threadIdx.x;
    for (int k = tid; k < 2 * MZP * (HID / 2); k += 1024) sT[k] = Tb32[k];
    __syncthreads();

    int lane = tid & 63, wv = tid >> 6;          // 16 waves/block, 1 node/wave
    int hi   = lane >> 5;                        // half index: 0 -> edge 2k, 1 -> edge 2k+1
    int l32  = lane & 31;
    int h4   = l32 * 4;                          // 4 floats per lane (both halves cover h 0..127)
    int l2   = l32 * 2;                          // uint32-pair index into sT rows
    uint32 fb4 = (uint32)l32 << 4;               // byte offset within ftab row
    int nov  = *ovfcnt;
    if (nov > OVF_CAP) nov = OVF_CAP;
    int nW = gridDim.x << 4;                     // total waves

    int n = (blockIdx.x << 4) + wv;
    int degC = 0, plvC = SENT;
    if (n < N) { degC = cnt[n]; plvC = payload[(size_t)n * PAD + l32]; }

    while (n < N) {
        // prefetch next node's metadata under this node's compute
        int n2 = n + nW;
        int degN = 0, plvN = SENT;
        if (n2 < N) { degN = cnt[n2]; plvN = payload[(size_t)n2 * PAD + l32]; }

        int deg = degC;
        int cb  = deg < PAD ? deg : PAD;
        int plv = (l32 < cb) ? plvC : SENT;      // in-register sentinel pad (prefetch-safe)
        int nit = (cb + 1) >> 1;

        float ax = 0.f, ay = 0.f, az = 0.f, aw = 0.f;
        if (nit > 0) {
            // pipeline prologue: iter0 fully issued, iter1 global issued
            int pl0 = PLSEL(plv, 0);
            float4 f0 = FLOAD(pl0);
            uint2 ua, ub; TL(pl0, ua, ub);
            int plL = PLSEL(plv, 1);
            float4 f1 = FLOAD(plL);
#pragma unroll 2
            for (int k = 0; k < nit; ++k) {
                int pl2 = PLSEL(plv, k + 2);             // lookahead lanes <=35: always valid/sentinel
                float4 f2 = FLOAD(pl2);                  // global, 2 iters ahead
                uint2 va, vb; TL(plL, va, vb);           // LDS, 1 iter ahead
                COMPUTE(f0, ua, ub);                     // current iteration
                f0 = f1; f1 = f2;
                ua = va; ub = vb;
                plL = pl2;
            }
        }
        // overflow edges (deg > PAD): owning wave folds them in (list empty in practice)
        if (deg > PAD && nov > 0) {
            for (int o = 0; o < nov; ++o) {
                int2 v = ovfbuf[o];
                if (v.x == n) {
                    int pl = v.y;
                    float4 f_ = FLOAD(pl);
                    uint2 ua_, ub_; TL(pl, ua_, ub_);
                    COMPUTE(f_, ua_, ub_);
                }
            }
        }
        // merge the two half-wave accumulators (same h range)
        ax += __shfl_xor(ax, 32);
        ay += __shfl_xor(ay, 32);
        az += __shfl_xor(az, 32);
        aw += __shfl_xor(aw, 32);
        if (hi == 0) {
            float s = (deg > 0) ? LN2 / (float)deg : 0.0f;   // ln2 folds the exp2-domain scale back
            float4 o4;
            o4.x = ax * s; o4.y = ay * s; o4.z = az * s; o4.w = aw * s;
            *(float4*)(out + (size_t)n * HID + h4) = o4;     // 512B contiguous row per wave
        }
        n = n2; degC = degN; plvC = plvN;
    }
}

// ---------- launch ----------
extern "C" void kernel_launch(void* const* d_in, const int* in_sizes, int n_in,
                              void* d_out, int out_size, void* d_ws, size_t ws_size,
                              hipStream_t stream) {
    const int*   z     = (const int*)d_in[0];
    const float* pos   = (const float*)d_in[1];
    const int*   ei    = (const int*)d_in[2];
    const float* freq  = (const float*)d_in[3];
    const float* emb   = (const float*)d_in[4];
    const float* W_rbf = (const float*)d_in[5];
    const float* b_rbf = (const float*)d_in[6];
    const float* W_lin = (const float*)d_in[7];
    const float* b_lin = (const float*)d_in[8];

    int N    = in_sizes[0];
    int E    = in_sizes[2] / 2;
    int MAXZ = in_sizes[4] / HID;   // 95 == MZ
    float* out = (float*)d_out;

    int N_pad = ((N + 1024) / 1024) * 1024;   // multiple of 1024, strictly > N

    char* ws = (char*)d_ws;
    size_t off = 0;
    auto alloc = [&](size_t bytes) { char* p = ws + off; off = (off + bytes + 255) & ~(size_t)255; return p; };
    int*   cnt     = (int*)alloc((size_t)N_pad * 4);     // N_pad*4 is 256-aligned
    int*   ovfcnt  = (int*)alloc(256);                   // adjacent to cnt for one memset
    __hip_bfloat16* Tb = (__hip_bfloat16*)alloc((size_t)2 * (MAXZ + 1) * HID * 2);
    float* ftab    = (float*)alloc((size_t)(TABN + 1) * HID * 4);
    int*   payload = (int*)alloc((size_t)N_pad * PAD * 4);
    int2*  ovfbuf  = (int2*)alloc((size_t)OVF_CAP * 8);
    float4* pos4   = (float4*)alloc((size_t)N_pad * 16);

    hipMemsetAsync(cnt, 0, (size_t)N_pad * 4 + 256, stream);   // zeros cnt + ovfcnt

    int nTabs = 2 * (MAXZ + 1) + (TABN + FTR) / FTR + (N + HID - 1) / HID;
    tabs_pack_k<<<nTabs, HID, 0, stream>>>(emb, W_lin, freq, W_rbf, b_rbf, b_lin,
                                           pos, z, Tb, ftab, pos4, MAXZ, N);
    edge_k<<<(E + 255) / 256, 256, 0, stream>>>(ei, pos4, cnt, payload, ovfcnt, ovfbuf, E);
    gather_k<<<512, 1024, 0, stream>>>(cnt, payload, (const uint32*)Tb, ftab,
                                       ovfcnt, ovfbuf, out, N);
}

// Round 5
// 180.151 us; speedup vs baseline: 1.1170x; 1.1170x over previous
//
#include <hip/hip_runtime.h>
#include <hip/hip_bf16.h>
#include <math.h>

#define HID 128
#define NRAD 6
#define TABN 4096          // nearest-neighbor table rows 0..TABN (row TABN = 0, x>=1 gate)
#define CUTOFF_INV 0.2f
#define MZ 95
#define MZP (MZ + 1)       // +1 sentinel row (index 95, huge-negative -> silu contribution == 0)
#define SENT ((MZ << 13) | (MZ << 20))
#define PAD 32             // padded-CSR slots per node (one 128B line); overflow -> spill list
#define OVF_CAP 65536
#define FTR 8              // ftab rows computed per block (W3 reuse x8)
#define LOG2E 1.4426950408889634f
#define LN2   0.6931471805599453f

typedef unsigned int uint32;
typedef __attribute__((ext_vector_type(2))) float f2;

// ---------- K1 (fused): bf16 T1(+b_lin)/T2 (+sentinel row) + ftab + edge pass ----------
// T1/T2/ftab stored PRE-SCALED by log2(e); gather evaluates silu in exp2 domain.
__global__ void build1(const float* __restrict__ emb, const float* __restrict__ W_lin,
                       const float* __restrict__ freq, const float* __restrict__ W_rbf,
                       const float* __restrict__ b_rbf, const float* __restrict__ b_lin,
                       const int* __restrict__ ei, const float* __restrict__ pos,
                       const int* __restrict__ z,
                       __hip_bfloat16* __restrict__ Tb, float* __restrict__ ftab,
                       int* __restrict__ cnt, int* __restrict__ payload,
                       int* __restrict__ ovfcnt, int2* __restrict__ ovfbuf,
                       int MAXZ, int E) {
    __shared__ float sh[FTR * HID];
    int h   = threadIdx.x;
    int bid = blockIdx.x;
    int nT  = 2 * (MAXZ + 1);
    int nF  = (TABN + FTR) / FTR;          // 513 blocks cover rows 0..4103 (clamped to TABN)
    if (bid < nT) {
        int zz = bid >> 1, s = bid & 1;
        if (zz == MAXZ) {                  // sentinel row: huge-neg => sigmoid==0 => zero contribution
            Tb[(size_t)(s * (MAXZ + 1) + zz) * HID + h] = __float2bfloat16(-86.5f);
            return;
        }
        sh[h] = emb[zz * HID + h];
        __syncthreads();
        const float* W = W_lin + (size_t)s * HID * HID;
        float acc = (s == 0) ? b_lin[h] : 0.f;   // fold bias into T1
#pragma unroll 8
        for (int k = 0; k < HID; ++k) acc = fmaf(sh[k], W[k * HID + h], acc);
        Tb[(size_t)(s * (MAXZ + 1) + zz) * HID + h] = __float2bfloat16(acc * LOG2E);
    } else if (bid < nT + nF) {
        int t0 = (bid - nT) * FTR;
        for (int r = 0; r < FTR; ++r) {
            int t = t0 + r;
            float rbf[NRAD];
            if (t == 0) {
#pragma unroll
                for (int k = 0; k < NRAD; ++k) rbf[k] = freq[k];   // lim x->0 env*sin(fx)=f
            } else if (t >= TABN) {
#pragma unroll
                for (int k = 0; k < NRAD; ++k) rbf[k] = 0.f;       // envelope gate x>=1
            } else {
                float x  = (float)t / (float)TABN;
                float x2 = x * x, x5 = x2 * x2 * x;
                float env = 1.f / x + x5 * (-28.f + x * (48.f + x * (-21.f)));
#pragma unroll
                for (int k = 0; k < NRAD; ++k) rbf[k] = env * sinf(freq[k] * x);
            }
            float pre = b_rbf[h];
#pragma unroll
            for (int k = 0; k < NRAD; ++k) pre = fmaf(rbf[k], W_rbf[k * HID + h], pre);
            sh[r * HID + h] = pre / (1.f + __expf(-pre));   // precise silu (once per table row)
        }
        __syncthreads();
        const float* W3 = W_lin + (size_t)2 * HID * HID;
        float acc[FTR];
#pragma unroll
        for (int r = 0; r < FTR; ++r) acc[r] = 0.f;
#pragma unroll 4
        for (int k = 0; k < HID; ++k) {
            float w = W3[k * HID + h];          // one load feeds 8 FMAs
#pragma unroll
            for (int r = 0; r < FTR; ++r) acc[r] = fmaf(sh[r * HID + k], w, acc[r]);
        }
        for (int r = 0; r < FTR; ++r) {
            int t = t0 + r;
            if (t <= TABN) ftab[(size_t)t * HID + h] = acc[r] * LOG2E;
        }
    } else {
        // edge pass: distance -> table index, rank via one atomic, direct padded write
        int e = (bid - nT - nF) * HID + h;
        if (e < E) {
            int i = ei[e];
            int j = ei[E + e];
            float dx = pos[3 * i]     - pos[3 * j];
            float dy = pos[3 * i + 1] - pos[3 * j + 1];
            float dz = pos[3 * i + 2] - pos[3 * j + 2];
            float d  = sqrtf(dx * dx + dy * dy + dz * dz);
            float u  = fminf(d * CUTOFF_INV, 1.0f) * (float)TABN;
            int   ti = (int)(u + 0.5f);          // nearest
            if (ti > TABN) ti = TABN;
            int pl = ti | (z[i] << 13) | (z[j] << 20);
            int r  = atomicAdd(&cnt[j], 1);
            if (r < PAD) {
                payload[(size_t)j * PAD + r] = pl;
            } else {
                int o = atomicAdd(ovfcnt, 1);
                if (o < OVF_CAP) ovfbuf[o] = make_int2(j, pl);
            }
        }
    }
}

// 2^(-x) in one instruction (neg folded as src modifier)
__device__ __forceinline__ float exp2neg(float x) {
    float r; asm("v_exp_f32 %0, -%1" : "=v"(r) : "v"(x)); return r;
}

// ftab f2 fragment: SGPR pl -> SALU row offset, + per-lane byte offset
#define FLOAD(pl_) (*(const f2*)((const char*)ftab + (uint32)((((pl_) & 0x1FFF) << 9) + fbyte)))

// LDS bf16-pair fragments (one uint32 per lane): SGPR row base + per-lane index
#define TLA(pl_) sT[((((pl_) >> 13) & 0x7F) << 6) + lane]
#define TLB(pl_) sT[sB + ((((pl_) >> 20) & 0x7F) << 6) + lane]

// packed silu accumulate for 2 h-values (exp2 domain)
#define COMPUTE(f_, ua_, ub_) do {                                             \
    f2 A_, B_, P_, E_, R_;                                                     \
    A_.x = __uint_as_float((ua_) << 16);                                       \
    A_.y = __uint_as_float((ua_) & 0xFFFF0000u);                               \
    B_.x = __uint_as_float((ub_) << 16);                                       \
    B_.y = __uint_as_float((ub_) & 0xFFFF0000u);                               \
    P_ = (A_ + B_) + f_;                      /* v_pk_add_f32 x2 */            \
    E_.x = exp2neg(P_.x);  E_.y = exp2neg(P_.y);                               \
    E_ = E_ + onev;                           /* 1 + 2^-p */                   \
    R_.x = __builtin_amdgcn_rcpf(E_.x);                                        \
    R_.y = __builtin_amdgcn_rcpf(E_.y);                                        \
    acc = __builtin_elementwise_fma(P_, R_, acc);  /* v_pk_fma_f32 */          \
} while (0)

// ---------- gather: 1 node/wave (scalarized), 1 edge/iter, 64 lanes x 2h, pipelined ----------
__launch_bounds__(1024)
__global__ void gather_k(const int* __restrict__ cnt, const int* __restrict__ payload,
                         const uint32* __restrict__ Tb32, const float* __restrict__ ftab,
                         const int* __restrict__ ovfcnt, const int2* __restrict__ ovfbuf,
                         float* __restrict__ out, int N) {
    __shared__ uint32 sT[2 * MZP * (HID / 2)];   // 49152 B, bf16 pairs (incl sentinel rows)
    int tid = threadIdx.x;
    for (int k = tid; k < 2 * MZP * (HID / 2); k += 1024) sT[k] = Tb32[k];
    __syncthreads();

    const int sB = MZP * (HID / 2);              // T2 base (uint32 units)
    int lane = tid & 63;
    int l32  = lane & 31;                        // payload slot mirror (readlane <=33 safe)
    int wv   = __builtin_amdgcn_readfirstlane(tid >> 6);   // uniform wave id 0..15
    uint32 fbyte = (uint32)lane << 3;            // 2 floats per lane in ftab row
    f2 onev; onev.x = 1.f; onev.y = 1.f;
    int nov  = __builtin_amdgcn_readfirstlane(*ovfcnt);
    if (nov > OVF_CAP) nov = OVF_CAP;
    int nW = gridDim.x << 4;                     // total waves

    int n = (blockIdx.x << 4) + wv;              // SGPR node index
    int degC = 0, plvC = SENT;
    if (n < N) {
        degC = __builtin_amdgcn_readfirstlane(cnt[n]);
        plvC = payload[(size_t)n * PAD + l32];
    }

    while (n < N) {
        // prefetch next node's metadata under this node's compute
        int n2 = n + nW;
        int degN = 0, plvN = SENT;
        if (n2 < N) {
            degN = __builtin_amdgcn_readfirstlane(cnt[n2]);
            plvN = payload[(size_t)n2 * PAD + l32];
        }

        int deg = degC;                          // SGPR
        int cb  = deg < PAD ? deg : PAD;         // SGPR
        int plv = (l32 < cb) ? plvC : SENT;      // sentinel pad (keeps lookahead addrs in-bounds)

        f2 acc; acc.x = 0.f; acc.y = 0.f;
        if (cb > 0) {
            int pl0 = __builtin_amdgcn_readlane(plv, 0);    // SGPR broadcast
            f2 f0 = FLOAD(pl0);
            uint32 ua = TLA(pl0), ub = TLB(pl0);
            int plL = __builtin_amdgcn_readlane(plv, 1);
            f2 f1 = FLOAD(plL);
#pragma unroll 2
            for (int k = 0; k < cb; ++k) {
                int pln = __builtin_amdgcn_readlane(plv, k + 2);  // lanes <=33: mirrored, valid
                f2 fn = FLOAD(pln);                       // global, 2 iters ahead
                uint32 va = TLA(plL), vb = TLB(plL);      // LDS, 1 iter ahead
                COMPUTE(f0, ua, ub);                      // current edge
                f0 = f1; f1 = fn;
                ua = va; ub = vb;
                plL = pln;
            }
        }
        // overflow edges (deg > PAD): owning wave folds them in (list empty in practice)
        if (deg > PAD && nov > 0) {
            for (int o = 0; o < nov; ++o) {
                int2 v = ovfbuf[o];
                int jn = __builtin_amdgcn_readfirstlane(v.x);
                if (jn == n) {
                    int pl = __builtin_amdgcn_readfirstlane(v.y);
                    f2 f_ = FLOAD(pl);
                    uint32 ua_ = TLA(pl), ub_ = TLB(pl);
                    COMPUTE(f_, ua_, ub_);
                }
            }
        }
        float s = (deg > 0) ? LN2 / (float)deg : 0.0f;   // ln2 folds the exp2-domain scale back
        f2 o2; o2.x = acc.x * s; o2.y = acc.y * s;
        *(f2*)(out + (size_t)n * HID + (lane << 1)) = o2;  // 512B contiguous row per wave
        n = n2; degC = degN; plvC = plvN;
    }
}

// ---------- launch ----------
extern "C" void kernel_launch(void* const* d_in, const int* in_sizes, int n_in,
                              void* d_out, int out_size, void* d_ws, size_t ws_size,
                              hipStream_t stream) {
    const int*   z     = (const int*)d_in[0];
    const float* pos   = (const float*)d_in[1];
    const int*   ei    = (const int*)d_in[2];
    const float* freq  = (const float*)d_in[3];
    const float* emb   = (const float*)d_in[4];
    const float* W_rbf = (const float*)d_in[5];
    const float* b_rbf = (const float*)d_in[6];
    const float* W_lin = (const float*)d_in[7];
    const float* b_lin = (const float*)d_in[8];

    int N    = in_sizes[0];
    int E    = in_sizes[2] / 2;
    int MAXZ = in_sizes[4] / HID;   // 95 == MZ
    float* out = (float*)d_out;

    int N_pad = ((N + 1024) / 1024) * 1024;   // multiple of 1024, strictly > N

    char* ws = (char*)d_ws;
    size_t off = 0;
    auto alloc = [&](size_t bytes) { char* p = ws + off; off = (off + bytes + 255) & ~(size_t)255; return p; };
    int*   cnt     = (int*)alloc((size_t)N_pad * 4);     // N_pad*4 is 256-aligned
    int*   ovfcnt  = (int*)alloc(256);                   // adjacent to cnt for one memset
    __hip_bfloat16* Tb = (__hip_bfloat16*)alloc((size_t)2 * (MAXZ + 1) * HID * 2);
    float* ftab    = (float*)alloc((size_t)(TABN + 1) * HID * 4);
    int*   payload = (int*)alloc((size_t)N_pad * PAD * 4);
    int2*  ovfbuf  = (int2*)alloc((size_t)OVF_CAP * 8);

    hipMemsetAsync(cnt, 0, (size_t)N_pad * 4 + 256, stream);   // zeros cnt + ovfcnt

    int nBuild = 2 * (MAXZ + 1) + (TABN + FTR) / FTR + (E + HID - 1) / HID;
    build1<<<nBuild, HID, 0, stream>>>(emb, W_lin, freq, W_rbf, b_rbf, b_lin,
                                       ei, pos, z, Tb, ftab, cnt, payload,
                                       ovfcnt, ovfbuf, MAXZ, E);
    gather_k<<<512, 1024, 0, stream>>>(cnt, payload, (const uint32*)Tb, ftab,
                                       ovfcnt, ovfbuf, out, N);
}

// Round 6
// 178.570 us; speedup vs baseline: 1.1269x; 1.0089x over previous
//
#include <hip/hip_runtime.h>
#include <hip/hip_bf16.h>
#include <math.h>

#define HID 128
#define NRAD 6
#define TABN 4096          // nearest-neighbor table rows 0..TABN (row TABN = 0, x>=1 gate)
#define CUTOFF_INV 0.2f
#define MZ 95
#define MZP (MZ + 1)       // +1 sentinel row (index 95, huge-negative -> silu contribution == 0)
#define SENT ((MZ << 13) | (MZ << 20))
#define PAD 32             // padded-CSR slots per node (one 128B line); overflow -> spill list
#define OVF_CAP 65536
#define FTR 8              // ftab rows computed per block (W3 reuse x8)
#define LOG2E 1.4426950408889634f
#define LN2   0.6931471805599453f

typedef unsigned int uint32;
typedef __attribute__((ext_vector_type(2))) float f2;

// ---------- K1 (fused): bf16 T1(+b_lin)/T2 (+sentinel row) + ftab + edge pass ----------
// T1/T2/ftab stored PRE-SCALED by log2(e); gather evaluates silu in exp2 domain.
__global__ void build1(const float* __restrict__ emb, const float* __restrict__ W_lin,
                       const float* __restrict__ freq, const float* __restrict__ W_rbf,
                       const float* __restrict__ b_rbf, const float* __restrict__ b_lin,
                       const int* __restrict__ ei, const float* __restrict__ pos,
                       const int* __restrict__ z,
                       __hip_bfloat16* __restrict__ Tb, float* __restrict__ ftab,
                       int* __restrict__ cnt, int* __restrict__ payload,
                       int* __restrict__ ovfcnt, int2* __restrict__ ovfbuf,
                       int MAXZ, int E) {
    __shared__ float sh[FTR * HID];
    int h   = threadIdx.x;
    int bid = blockIdx.x;
    int nT  = 2 * (MAXZ + 1);
    int nF  = (TABN + FTR) / FTR;          // 513 blocks cover rows 0..4103 (clamped to TABN)
    if (bid < nT) {
        int zz = bid >> 1, s = bid & 1;
        if (zz == MAXZ) {                  // sentinel row: huge-neg => sigmoid==0 => zero contribution
            Tb[(size_t)(s * (MAXZ + 1) + zz) * HID + h] = __float2bfloat16(-86.5f);
            return;
        }
        sh[h] = emb[zz * HID + h];
        __syncthreads();
        const float* W = W_lin + (size_t)s * HID * HID;
        float acc = (s == 0) ? b_lin[h] : 0.f;   // fold bias into T1
#pragma unroll 8
        for (int k = 0; k < HID; ++k) acc = fmaf(sh[k], W[k * HID + h], acc);
        Tb[(size_t)(s * (MAXZ + 1) + zz) * HID + h] = __float2bfloat16(acc * LOG2E);
    } else if (bid < nT + nF) {
        int t0 = (bid - nT) * FTR;
        for (int r = 0; r < FTR; ++r) {
            int t = t0 + r;
            float rbf[NRAD];
            if (t == 0) {
#pragma unroll
                for (int k = 0; k < NRAD; ++k) rbf[k] = freq[k];   // lim x->0 env*sin(fx)=f
            } else if (t >= TABN) {
#pragma unroll
                for (int k = 0; k < NRAD; ++k) rbf[k] = 0.f;       // envelope gate x>=1
            } else {
                float x  = (float)t / (float)TABN;
                float x2 = x * x, x5 = x2 * x2 * x;
                float env = 1.f / x + x5 * (-28.f + x * (48.f + x * (-21.f)));
#pragma unroll
                for (int k = 0; k < NRAD; ++k) rbf[k] = env * sinf(freq[k] * x);
            }
            float pre = b_rbf[h];
#pragma unroll
            for (int k = 0; k < NRAD; ++k) pre = fmaf(rbf[k], W_rbf[k * HID + h], pre);
            sh[r * HID + h] = pre / (1.f + __expf(-pre));   // precise silu (once per table row)
        }
        __syncthreads();
        const float* W3 = W_lin + (size_t)2 * HID * HID;
        float acc[FTR];
#pragma unroll
        for (int r = 0; r < FTR; ++r) acc[r] = 0.f;
#pragma unroll 4
        for (int k = 0; k < HID; ++k) {
            float w = W3[k * HID + h];          // one load feeds 8 FMAs
#pragma unroll
            for (int r = 0; r < FTR; ++r) acc[r] = fmaf(sh[r * HID + k], w, acc[r]);
        }
        for (int r = 0; r < FTR; ++r) {
            int t = t0 + r;
            if (t <= TABN) ftab[(size_t)t * HID + h] = acc[r] * LOG2E;
        }
    } else {
        // edge pass: distance -> table index, rank via one atomic, direct padded write
        int e = (bid - nT - nF) * HID + h;
        if (e < E) {
            int i = ei[e];
            int j = ei[E + e];
            float dx = pos[3 * i]     - pos[3 * j];
            float dy = pos[3 * i + 1] - pos[3 * j + 1];
            float dz = pos[3 * i + 2] - pos[3 * j + 2];
            float d  = sqrtf(dx * dx + dy * dy + dz * dz);
            float u  = fminf(d * CUTOFF_INV, 1.0f) * (float)TABN;
            int   ti = (int)(u + 0.5f);          // nearest
            if (ti > TABN) ti = TABN;
            int pl = ti | (z[i] << 13) | (z[j] << 20);
            int r  = atomicAdd(&cnt[j], 1);
            if (r < PAD) {
                payload[(size_t)j * PAD + r] = pl;
            } else {
                int o = atomicAdd(ovfcnt, 1);
                if (o < OVF_CAP) ovfbuf[o] = make_int2(j, pl);
            }
        }
    }
}

// 2^(-x) in one instruction (neg folded as src modifier)
__device__ __forceinline__ float exp2neg(float x) {
    float r; asm("v_exp_f32 %0, -%1" : "=v"(r) : "v"(x)); return r;
}

#define RL(pv_, idx_) __builtin_amdgcn_readlane((pv_), (idx_))

// ftab f2 fragment: SGPR pl -> SALU row offset, + per-lane byte offset
#define FLOAD(pl_) (*(const f2*)((const char*)ftab + (uint32)((((pl_) & 0x1FFF) << 9) + fbyte)))

// LDS bf16-pair fragments (one uint32 per lane): SGPR row base + per-lane index
#define TLA(pl_) sT[((((pl_) >> 13) & 0x7F) << 6) + lane]
#define TLB(pl_) sT[sB + ((((pl_) >> 20) & 0x7F) << 6) + lane]

// packed silu accumulate for 2 h-values (exp2 domain)
#define COMPUTE(f_, ua_, ub_) do {                                             \
    f2 A_, B_, P_, E_, R_;                                                     \
    A_.x = __uint_as_float((ua_) << 16);                                       \
    A_.y = __uint_as_float((ua_) & 0xFFFF0000u);                               \
    B_.x = __uint_as_float((ub_) << 16);                                       \
    B_.y = __uint_as_float((ub_) & 0xFFFF0000u);                               \
    P_ = (A_ + B_) + f_;                      /* v_pk_add_f32 x2 */            \
    E_.x = exp2neg(P_.x);  E_.y = exp2neg(P_.y);                               \
    E_ = E_ + onev;                           /* 1 + 2^-p */                   \
    R_.x = __builtin_amdgcn_rcpf(E_.x);                                        \
    R_.y = __builtin_amdgcn_rcpf(E_.y);                                        \
    acc = __builtin_elementwise_fma(P_, R_, acc);  /* v_pk_fma_f32 */          \
} while (0)

// ---------- gather: 1 node/wave (scalarized), deep pipeline (G:3-ahead, LDS:2-ahead) ----------
__launch_bounds__(1024)
__global__ void gather_k(const int* __restrict__ cnt, const int* __restrict__ payload,
                         const uint32* __restrict__ Tb32, const float* __restrict__ ftab,
                         const int* __restrict__ ovfcnt, const int2* __restrict__ ovfbuf,
                         float* __restrict__ out, int N) {
    __shared__ uint32 sT[2 * MZP * (HID / 2)];   // 49152 B, bf16 pairs (incl sentinel rows)
    int tid = threadIdx.x;
    for (int k = tid; k < 2 * MZP * (HID / 2); k += 1024) sT[k] = Tb32[k];
    __syncthreads();

    const int sB = MZP * (HID / 2);              // T2 base (uint32 units)
    int lane = tid & 63;
    int l32  = lane & 31;                        // payload slot mirror (readlane <=34 safe)
    int wv   = __builtin_amdgcn_readfirstlane(tid >> 6);   // uniform wave id 0..15
    uint32 fbyte = (uint32)lane << 3;            // 2 floats per lane in ftab row
    f2 onev; onev.x = 1.f; onev.y = 1.f;
    int nov  = __builtin_amdgcn_readfirstlane(*ovfcnt);
    if (nov > OVF_CAP) nov = OVF_CAP;
    int nW = gridDim.x << 4;                     // total waves

    int n = (blockIdx.x << 4) + wv;              // SGPR node index
    int degC = 0, plvC = SENT;
    if (n < N) {
        degC = __builtin_amdgcn_readfirstlane(cnt[n]);
        plvC = payload[(size_t)n * PAD + l32];
    }

    while (n < N) {
        // prefetch next node's metadata under this node's compute
        int n2 = n + nW;
        int degN = 0, plvN = SENT;
        if (n2 < N) {
            degN = __builtin_amdgcn_readfirstlane(cnt[n2]);
            plvN = payload[(size_t)n2 * PAD + l32];
        }

        int deg = degC;                          // SGPR
        int cb  = deg < PAD ? deg : PAD;         // SGPR
        int plv = (l32 < cb) ? plvC : SENT;      // sentinel pad (keeps lookahead addrs in-bounds)

        f2 acc; acc.x = 0.f; acc.y = 0.f;
        if (cb > 0) {
            // prologue: 3 global stages, 2 LDS stages in flight
            int pl0 = RL(plv, 0), pl1 = RL(plv, 1), pl2 = RL(plv, 2);
            f2 g0 = FLOAD(pl0), g1 = FLOAD(pl1), g2 = FLOAD(pl2);
            uint32 ua0 = TLA(pl0), ub0 = TLB(pl0);
            uint32 ua1 = TLA(pl1), ub1 = TLB(pl1);
#pragma unroll 4
            for (int k = 0; k < cb; ++k) {
                int pl3 = RL(plv, k + 3);                 // lanes <=34: mirrored, valid
                f2 g3 = FLOAD(pl3);                       // global, 3 iters ahead (~L2 latency)
                uint32 ua2 = TLA(pl2), ub2 = TLB(pl2);    // LDS, 2 iters ahead (~LDS latency)
                COMPUTE(g0, ua0, ub0);                    // current edge
                g0 = g1; g1 = g2; g2 = g3;
                ua0 = ua1; ub0 = ub1;
                ua1 = ua2; ub1 = ub2;
                pl2 = pl3;
            }
        }
        // overflow edges (deg > PAD): owning wave folds them in (list empty in practice)
        if (deg > PAD && nov > 0) {
            for (int o = 0; o < nov; ++o) {
                int2 v = ovfbuf[o];
                int jn = __builtin_amdgcn_readfirstlane(v.x);
                if (jn == n) {
                    int pl = __builtin_amdgcn_readfirstlane(v.y);
                    f2 f_ = FLOAD(pl);
                    uint32 ua_ = TLA(pl), ub_ = TLB(pl);
                    COMPUTE(f_, ua_, ub_);
                }
            }
        }
        float s = (deg > 0) ? LN2 / (float)deg : 0.0f;   // ln2 folds the exp2-domain scale back
        f2 o2; o2.x = acc.x * s; o2.y = acc.y * s;
        *(f2*)(out + (size_t)n * HID + (lane << 1)) = o2;  // 512B contiguous row per wave
        n = n2; degC = degN; plvC = plvN;
    }
}

// ---------- launch ----------
extern "C" void kernel_launch(void* const* d_in, const int* in_sizes, int n_in,
                              void* d_out, int out_size, void* d_ws, size_t ws_size,
                              hipStream_t stream) {
    const int*   z     = (const int*)d_in[0];
    const float* pos   = (const float*)d_in[1];
    const int*   ei    = (const int*)d_in[2];
    const float* freq  = (const float*)d_in[3];
    const float* emb   = (const float*)d_in[4];
    const float* W_rbf = (const float*)d_in[5];
    const float* b_rbf = (const float*)d_in[6];
    const float* W_lin = (const float*)d_in[7];
    const float* b_lin = (const float*)d_in[8];

    int N    = in_sizes[0];
    int E    = in_sizes[2] / 2;
    int MAXZ = in_sizes[4] / HID;   // 95 == MZ
    float* out = (float*)d_out;

    int N_pad = ((N + 1024) / 1024) * 1024;   // multiple of 1024, strictly > N

    char* ws = (char*)d_ws;
    size_t off = 0;
    auto alloc = [&](size_t bytes) { char* p = ws + off; off = (off + bytes + 255) & ~(size_t)255; return p; };
    int*   cnt     = (int*)alloc((size_t)N_pad * 4);     // N_pad*4 is 256-aligned
    int*   ovfcnt  = (int*)alloc(256);                   // adjacent to cnt for one memset
    __hip_bfloat16* Tb = (__hip_bfloat16*)alloc((size_t)2 * (MAXZ + 1) * HID * 2);
    float* ftab    = (float*)alloc((size_t)(TABN + 1) * HID * 4);
    int*   payload = (int*)alloc((size_t)N_pad * PAD * 4);
    int2*  ovfbuf  = (int2*)alloc((size_t)OVF_CAP * 8);

    hipMemsetAsync(cnt, 0, (size_t)N_pad * 4 + 256, stream);   // zeros cnt + ovfcnt

    int nBuild = 2 * (MAXZ + 1) + (TABN + FTR) / FTR + (E + HID - 1) / HID;
    build1<<<nBuild, HID, 0, stream>>>(emb, W_lin, freq, W_rbf, b_rbf, b_lin,
                                       ei, pos, z, Tb, ftab, cnt, payload,
                                       ovfcnt, ovfbuf, MAXZ, E);
    gather_k<<<512, 1024, 0, stream>>>(cnt, payload, (const uint32*)Tb, ftab,
                                       ovfcnt, ovfbuf, out, N);
}